// Round 11
// baseline (57.465 us; speedup 1.0000x reference)
//
#include <hip/hip_runtime.h>

#define FH 128
#define FW 128
#define CPLANE 490                 // 10*7*7 input channels; plane c_in serves bin (ph,pw)
#define NBATCH 4
#define NPLANES (NBATCH * CPLANE)  // 1960 = 8 * 245
#define SSCALE 0.0625f

// ws layout (ints). Total 60 + 4*2048 = 8252 ints = 33 KB (proven-safe band).
#define WS_CNT  0                  // [0..3] per-batch roi counts
#define WS_ROWS 4                  // [4..59] per-(b,ph) staging row bounds {rlo,rhi}
#define WS_LIST 60                 // [60 + b*R + slot] roi indices

typedef float f32x4 __attribute__((ext_vector_type(4)));

// ---- kernel A: one block per batch: bucket rois + exact row bounds ----------
__global__ __launch_bounds__(1024) void bucket_rois(const float* __restrict__ rois,
                                                    int R, int* __restrict__ ws) {
    const int b = blockIdx.x;
    __shared__ int cnt;
    __shared__ unsigned fymin[7], fymax[7];
    if (threadIdx.x == 0) cnt = 0;
    if (threadIdx.x < 7) { fymin[threadIdx.x] = 0x7F800000u; fymax[threadIdx.x] = 0u; }
    __syncthreads();

    for (int i = threadIdx.x; i < R; i += 1024) {
        const float* roi = rois + (size_t)i * 5;
        if ((int)roi[0] == b) {
            const int slot = atomicAdd(&cnt, 1);
            ws[WS_LIST + b * R + slot] = i;
            const float y1 = roi[2] * SSCALE;
            const float bh = fmaxf(roi[4] * SSCALE - y1, 0.1f) * (1.0f / 7.0f);
#pragma unroll
            for (int ph = 0; ph < 7; ++ph) {
                const float lo = y1 + ((float)ph + 0.25f) * bh;   // min sample y
                const float hi = y1 + ((float)ph + 0.75f) * bh;   // max sample y
                atomicMin(&fymin[ph], __float_as_uint(lo));       // y>=0: uint order == float order
                atomicMax(&fymax[ph], __float_as_uint(hi));
            }
        }
    }
    __syncthreads();
    if (threadIdx.x == 0) ws[WS_CNT + b] = cnt;
    if (threadIdx.x < 7) {
        const int ph = threadIdx.x;
        int rlo = 0, rhi = 127;
        if (cnt > 0) {
            const float lo = __uint_as_float(fymin[ph]);
            const float hi = __uint_as_float(fymax[ph]);
            rlo = min((int)fminf(lo, 126.0f), 126);        // first row any sample reads
            rhi = min((int)fminf(hi, 126.0f), 126) + 1;    // last row (bilinear +1, clamp-safe)
        }
        ws[WS_ROWS + (b * 7 + ph) * 2 + 0] = rlo;
        ws[WS_ROWS + (b * 7 + ph) * 2 + 1] = rhi;
    }
}

// ---- kernel B: one plane per block; row-trimmed LDS staging -----------------
// Round-9 proven structure: dynamic dispatch (block dies after one plane),
// XCD-chunked swizzle (write-merge in same-XCD L2), NT staging loads.
__global__ __launch_bounds__(1024) void psroi_plane_lds(const float* __restrict__ feat,
                                                        const float* __restrict__ rois,
                                                        const int* __restrict__ ws,
                                                        float* __restrict__ out, int R) {
    __shared__ float plane[FH * FW];   // 64 KB -> 2 blocks/CU, 32 waves/CU
    const int tid = threadIdx.x;
    const int bid = blockIdx.x;
    const int pl  = (bid & 7) * (NPLANES / 8) + (bid >> 3);  // bijective XCD chunking
    const int b    = pl / CPLANE;
    const int c_in = pl - b * CPLANE;
    const int pw   = c_in % 7;
    const int ph   = (c_in / 7) % 7;

    const int rlo = ws[WS_ROWS + (b * 7 + ph) * 2 + 0];
    const int rhi = ws[WS_ROWS + (b * 7 + ph) * 2 + 1];
    const int nq  = (rhi - rlo + 1) * (FW / 4);              // float4 count to stage

    // ---- stage rows [rlo, rhi]: pipelined NT loads -> LDS writes ----
    const f32x4* __restrict__ src = (const f32x4*)(feat + (size_t)pl * (FH * FW)) + rlo * (FW / 4);
    f32x4* __restrict__ plane4 = (f32x4*)plane;
    f32x4 s0, s1, s2, s3;
    if (0 * 1024 + tid < nq) s0 = __builtin_nontemporal_load(src + 0 * 1024 + tid);
    if (1 * 1024 + tid < nq) s1 = __builtin_nontemporal_load(src + 1 * 1024 + tid);
    if (2 * 1024 + tid < nq) s2 = __builtin_nontemporal_load(src + 2 * 1024 + tid);
    if (3 * 1024 + tid < nq) s3 = __builtin_nontemporal_load(src + 3 * 1024 + tid);
    if (0 * 1024 + tid < nq) plane4[0 * 1024 + tid] = s0;
    if (1 * 1024 + tid < nq) plane4[1 * 1024 + tid] = s1;
    if (2 * 1024 + tid < nq) plane4[2 * 1024 + tid] = s2;
    if (3 * 1024 + tid < nq) plane4[3 * 1024 + tid] = s3;
    __syncthreads();

    // ---- gather: 4 lanes per roi (one per bilinear sample) ----
    const int  nb   = ws[WS_CNT + b];
    const int* list = ws + WS_LIST + b * R;

    const int   sub = tid & 3;
    const float sy  = 0.25f + 0.5f * (float)(sub >> 1);
    const float sx  = 0.25f + 0.5f * (float)(sub & 1);

    for (int base = 0; base < nb; base += 256) {
        const int k = base + (tid >> 2);
        if (k < nb) {
            const int ri = list[k];
            const float* roi = rois + (size_t)ri * 5;   // hot 40 KB, cache-resident
            const float x1 = roi[1] * SSCALE;
            const float y1 = roi[2] * SSCALE;
            const float bw = fmaxf(roi[3] * SSCALE - x1, 0.1f) * (1.0f / 7.0f);
            const float bh = fmaxf(roi[4] * SSCALE - y1, 0.1f) * (1.0f / 7.0f);

            float y = y1 + ((float)ph + sy) * bh;
            y = fminf(fmaxf(y, 0.0f), 127.0f);
            float y0f = floorf(y);
            int   y0  = (int)y0f;
            float ly  = y - y0f;
            if (y0 > 126) { y0 = 126; ly = 1.0f; }   // y==127 -> full weight on row 127

            float x = x1 + ((float)pw + sx) * bw;
            x = fminf(fmaxf(x, 0.0f), 127.0f);
            float x0f = floorf(x);
            int   x0  = (int)x0f;
            float lx  = x - x0f;
            if (x0 > 126) { x0 = 126; lx = 1.0f; }

            const float* p = plane + (y0 - rlo) * FW + x0;
            const float v00 = p[0];
            const float v01 = p[1];
            const float v10 = p[FW];
            const float v11 = p[FW + 1];

            const float top = v00 + (v01 - v00) * lx;
            const float bot = v10 + (v11 - v10) * lx;
            float val = top + (bot - top) * ly;

            val += __shfl_xor(val, 1);
            val += __shfl_xor(val, 2);
            if (sub == 0) out[(size_t)ri * CPLANE + c_in] = val * 0.25f;
        }
    }
}

extern "C" void kernel_launch(void* const* d_in, const int* in_sizes, int n_in,
                              void* d_out, int out_size, void* d_ws, size_t ws_size,
                              hipStream_t stream) {
    const float* feat = (const float*)d_in[0];
    const float* rois = (const float*)d_in[1];
    float* out = (float*)d_out;
    int* ws = (int*)d_ws;

    const int R = in_sizes[1] / 5;   // 2048

    bucket_rois<<<NBATCH, 1024, 0, stream>>>(rois, R, ws);
    psroi_plane_lds<<<NPLANES, 1024, 0, stream>>>(feat, rois, ws, out, R);
}

// Round 12
// 36.781 us; speedup vs baseline: 1.5624x; 1.5624x over previous
//
#include <hip/hip_runtime.h>

#define FH 128
#define FW 128
#define CPLANE 490                 // 10*7*7 input channels; plane c_in serves bin (ph,pw)
#define NBATCH 4
#define NPLANES (NBATCH * CPLANE)  // 1960 = 8 * 245
#define SSCALE 0.0625f

// ws layout (ints). Total 60 + 4*2048 = 8252 ints = 33 KB (proven-safe band).
#define WS_CNT  0                  // [0..3] per-batch roi counts
#define WS_ROWS 4                  // [4..59] per-(b,ph) staging row bounds {rlo,rhi}
#define WS_LIST 60                 // [60 + b*R + slot] roi indices

typedef float f32x4 __attribute__((ext_vector_type(4)));

// ---- kernel A: one block per batch: bucket rois + exact row bounds ----------
// Register accumulation + wave shfl-reduce; ONE LDS atomic per wave per value
// (round 11's per-roi atomics serialized ~20us on 14 shared words).
__global__ __launch_bounds__(1024) void bucket_rois(const float* __restrict__ rois,
                                                    int R, int* __restrict__ ws) {
    const int b = blockIdx.x;
    __shared__ int cnt;
    __shared__ unsigned fymin[7], fymax[7];
    if (threadIdx.x == 0) cnt = 0;
    if (threadIdx.x < 7) { fymin[threadIdx.x] = 0x7F800000u; fymax[threadIdx.x] = 0u; }
    __syncthreads();

    float lo[7], hi[7];
#pragma unroll
    for (int p = 0; p < 7; ++p) { lo[p] = 1e30f; hi[p] = -1e30f; }

    for (int i = threadIdx.x; i < R; i += 1024) {
        const float* roi = rois + (size_t)i * 5;
        if ((int)roi[0] == b) {
            const int slot = atomicAdd(&cnt, 1);
            ws[WS_LIST + b * R + slot] = i;
            const float y1 = roi[2] * SSCALE;
            const float bh = fmaxf(roi[4] * SSCALE - y1, 0.1f) * (1.0f / 7.0f);
#pragma unroll
            for (int p = 0; p < 7; ++p) {
                lo[p] = fminf(lo[p], y1 + ((float)p + 0.25f) * bh);   // min sample y
                hi[p] = fmaxf(hi[p], y1 + ((float)p + 0.75f) * bh);   // max sample y
            }
        }
    }

    // wave-level butterfly reduce (6 steps), then one atomic per wave per word
#pragma unroll
    for (int p = 0; p < 7; ++p) {
#pragma unroll
        for (int off = 1; off < 64; off <<= 1) {
            lo[p] = fminf(lo[p], __shfl_xor(lo[p], off));
            hi[p] = fmaxf(hi[p], __shfl_xor(hi[p], off));
        }
    }
    if ((threadIdx.x & 63) == 0) {
#pragma unroll
        for (int p = 0; p < 7; ++p) {
            // clamp to >=0 so float-as-uint ordering is valid; empty-wave
            // sentinels become neutral (lo=1e30 stays huge, hi=-1e30 -> 0)
            atomicMin(&fymin[p], __float_as_uint(fmaxf(lo[p], 0.0f)));
            atomicMax(&fymax[p], __float_as_uint(fmaxf(hi[p], 0.0f)));
        }
    }
    __syncthreads();
    if (threadIdx.x == 0) ws[WS_CNT + b] = cnt;
    if (threadIdx.x < 7) {
        const int ph = threadIdx.x;
        int rlo = 0, rhi = 127;
        if (cnt > 0) {
            const float flo = __uint_as_float(fymin[ph]);
            const float fhi = __uint_as_float(fymax[ph]);
            rlo = min((int)fminf(flo, 126.0f), 126);        // first row any sample reads
            rhi = min((int)fminf(fhi, 126.0f), 126) + 1;    // last row (bilinear +1)
        }
        ws[WS_ROWS + (b * 7 + ph) * 2 + 0] = rlo;
        ws[WS_ROWS + (b * 7 + ph) * 2 + 1] = rhi;
    }
}

// ---- kernel B: one plane per block; row-trimmed LDS staging -----------------
// Round-9 proven structure: dynamic dispatch (block dies after one plane),
// XCD-chunked swizzle (write-merge in same-XCD L2), NT staging loads.
__global__ __launch_bounds__(1024) void psroi_plane_lds(const float* __restrict__ feat,
                                                        const float* __restrict__ rois,
                                                        const int* __restrict__ ws,
                                                        float* __restrict__ out, int R) {
    __shared__ float plane[FH * FW];   // 64 KB -> 2 blocks/CU, 32 waves/CU
    const int tid = threadIdx.x;
    const int bid = blockIdx.x;
    const int pl  = (bid & 7) * (NPLANES / 8) + (bid >> 3);  // bijective XCD chunking
    const int b    = pl / CPLANE;
    const int c_in = pl - b * CPLANE;
    const int pw   = c_in % 7;
    const int ph   = (c_in / 7) % 7;

    const int rlo = ws[WS_ROWS + (b * 7 + ph) * 2 + 0];
    const int rhi = ws[WS_ROWS + (b * 7 + ph) * 2 + 1];
    const int nq  = (rhi - rlo + 1) * (FW / 4);              // float4 count to stage

    // ---- stage rows [rlo, rhi]: pipelined NT loads -> LDS writes ----
    const f32x4* __restrict__ src = (const f32x4*)(feat + (size_t)pl * (FH * FW)) + rlo * (FW / 4);
    f32x4* __restrict__ plane4 = (f32x4*)plane;
    f32x4 s0, s1, s2, s3;
    if (0 * 1024 + tid < nq) s0 = __builtin_nontemporal_load(src + 0 * 1024 + tid);
    if (1 * 1024 + tid < nq) s1 = __builtin_nontemporal_load(src + 1 * 1024 + tid);
    if (2 * 1024 + tid < nq) s2 = __builtin_nontemporal_load(src + 2 * 1024 + tid);
    if (3 * 1024 + tid < nq) s3 = __builtin_nontemporal_load(src + 3 * 1024 + tid);
    if (0 * 1024 + tid < nq) plane4[0 * 1024 + tid] = s0;
    if (1 * 1024 + tid < nq) plane4[1 * 1024 + tid] = s1;
    if (2 * 1024 + tid < nq) plane4[2 * 1024 + tid] = s2;
    if (3 * 1024 + tid < nq) plane4[3 * 1024 + tid] = s3;
    __syncthreads();

    // ---- gather: 4 lanes per roi (one per bilinear sample) ----
    const int  nb   = ws[WS_CNT + b];
    const int* list = ws + WS_LIST + b * R;

    const int   sub = tid & 3;
    const float sy  = 0.25f + 0.5f * (float)(sub >> 1);
    const float sx  = 0.25f + 0.5f * (float)(sub & 1);

    for (int base = 0; base < nb; base += 256) {
        const int k = base + (tid >> 2);
        if (k < nb) {
            const int ri = list[k];
            const float* roi = rois + (size_t)ri * 5;   // hot 40 KB, cache-resident
            const float x1 = roi[1] * SSCALE;
            const float y1 = roi[2] * SSCALE;
            const float bw = fmaxf(roi[3] * SSCALE - x1, 0.1f) * (1.0f / 7.0f);
            const float bh = fmaxf(roi[4] * SSCALE - y1, 0.1f) * (1.0f / 7.0f);

            float y = y1 + ((float)ph + sy) * bh;
            y = fminf(fmaxf(y, 0.0f), 127.0f);
            float y0f = floorf(y);
            int   y0  = (int)y0f;
            float ly  = y - y0f;
            if (y0 > 126) { y0 = 126; ly = 1.0f; }   // y==127 -> full weight on row 127

            float x = x1 + ((float)pw + sx) * bw;
            x = fminf(fmaxf(x, 0.0f), 127.0f);
            float x0f = floorf(x);
            int   x0  = (int)x0f;
            float lx  = x - x0f;
            if (x0 > 126) { x0 = 126; lx = 1.0f; }

            const float* p = plane + (y0 - rlo) * FW + x0;
            const float v00 = p[0];
            const float v01 = p[1];
            const float v10 = p[FW];
            const float v11 = p[FW + 1];

            const float top = v00 + (v01 - v00) * lx;
            const float bot = v10 + (v11 - v10) * lx;
            float val = top + (bot - top) * ly;

            val += __shfl_xor(val, 1);
            val += __shfl_xor(val, 2);
            if (sub == 0) out[(size_t)ri * CPLANE + c_in] = val * 0.25f;
        }
    }
}

extern "C" void kernel_launch(void* const* d_in, const int* in_sizes, int n_in,
                              void* d_out, int out_size, void* d_ws, size_t ws_size,
                              hipStream_t stream) {
    const float* feat = (const float*)d_in[0];
    const float* rois = (const float*)d_in[1];
    float* out = (float*)d_out;
    int* ws = (int*)d_ws;

    const int R = in_sizes[1] / 5;   // 2048

    bucket_rois<<<NBATCH, 1024, 0, stream>>>(rois, R, ws);
    psroi_plane_lds<<<NPLANES, 1024, 0, stream>>>(feat, rois, ws, out, R);
}

// Round 13
// 36.715 us; speedup vs baseline: 1.5652x; 1.0018x over previous
//
#include <hip/hip_runtime.h>

#define FH 128
#define FW 128
#define CPLANE 490                 // 10*7*7 input channels; plane c_in serves bin (ph,pw)
#define NBATCH 4
#define NPLANES (NBATCH * CPLANE)  // 1960 = 8 * 245
#define SSCALE 0.0625f

typedef float f32x4 __attribute__((ext_vector_type(4)));

// Single fused kernel: one plane per block (XCD-chunked), self-built roi list.
// Phases: issue NT loads -> ballot-compact roi list in LDS (overlaps load
// latency) -> lift list to regs -> commit plane to LDS -> gather.
__global__ __launch_bounds__(1024, 8) void psroi_fused(const float* __restrict__ feat,
                                                       const float* __restrict__ rois,
                                                       float* __restrict__ out, int R) {
    __shared__ float plane[FH * FW];           // exactly 64 KB -> 2 blocks/CU
    int* const lint = (int*)plane;             // compacted roi list (ints 0..2047)
    int* const wtot = (int*)plane + (FH * FW - 16);  // 16 per-wave counts (tail region)

    const int tid = threadIdx.x;
    const int bid = blockIdx.x;
    const int pl  = (bid & 7) * (NPLANES / 8) + (bid >> 3);  // bijective XCD chunking
    const int b    = pl / CPLANE;
    const int c_in = pl - b * CPLANE;
    const int pw   = c_in % 7;
    const int ph   = (c_in / 7) % 7;

    // ---- phase 0: issue full-plane NT loads; they stay in flight below ----
    const f32x4* __restrict__ src = (const f32x4*)(feat + (size_t)pl * (FH * FW));
    f32x4 s0 = __builtin_nontemporal_load(src + 0 * 1024 + tid);
    f32x4 s1 = __builtin_nontemporal_load(src + 1 * 1024 + tid);
    f32x4 s2 = __builtin_nontemporal_load(src + 2 * 1024 + tid);
    f32x4 s3 = __builtin_nontemporal_load(src + 3 * 1024 + tid);

    // ---- phase 1: scan rois (2/thread), deterministic ballot compaction ----
    const int i0 = tid * 2, i1 = i0 + 1;
    bool m0 = false, m1 = false;
    if (i0 < R) m0 = ((int)rois[(size_t)i0 * 5] == b);
    if (i1 < R) m1 = ((int)rois[(size_t)i1 * 5] == b);
    const unsigned long long bl0 = __ballot(m0);
    const unsigned long long bl1 = __ballot(m1);
    const int w    = tid >> 6;
    const int lane = tid & 63;
    const unsigned long long below = ((unsigned long long)1 << lane) - 1;
    if (lane == 0) wtot[w] = __popcll(bl0) + __popcll(bl1);
    __syncthreads();

    int nb = 0, woff = 0;
#pragma unroll
    for (int ww = 0; ww < 16; ++ww) {
        const int c = wtot[ww];
        if (ww < w) woff += c;
        nb += c;
    }
    const int p0 = woff + __popcll(bl0 & below) + __popcll(bl1 & below);
    if (m0) lint[p0] = i0;
    if (m1) lint[p0 + (m0 ? 1 : 0)] = i1;
    __syncthreads();

    // ---- phase 2: lift my <=8 gather entries into named regs (rule #20) ----
    const int kb = tid >> 2;
    const int r0 = lint[kb];
    const int r1 = lint[kb + 256];
    const int r2 = lint[kb + 512];
    const int r3 = lint[kb + 768];
    const int r4 = lint[kb + 1024];
    const int r5 = lint[kb + 1280];
    const int r6 = lint[kb + 1536];
    const int r7 = lint[kb + 1792];
    __syncthreads();                 // list fully consumed; plane may overwrite

    // ---- phase 3: commit staged plane to LDS (vmcnt wait lands here) ----
    *(f32x4*)(plane + (0 * 1024 + tid) * 4) = s0;
    *(f32x4*)(plane + (1 * 1024 + tid) * 4) = s1;
    *(f32x4*)(plane + (2 * 1024 + tid) * 4) = s2;
    *(f32x4*)(plane + (3 * 1024 + tid) * 4) = s3;
    __syncthreads();

    // ---- phase 4: gather, 4 lanes per roi ----
    const int   sub = tid & 3;
    const float sy  = 0.25f + 0.5f * (float)(sub >> 1);
    const float sx  = 0.25f + 0.5f * (float)(sub & 1);

    auto gather = [&](int k, int ri) {
        if (k < nb) {
            const float* roi = rois + (size_t)ri * 5;   // hot 40 KB, cache-resident
            const float x1 = roi[1] * SSCALE;
            const float y1 = roi[2] * SSCALE;
            const float bw = fmaxf(roi[3] * SSCALE - x1, 0.1f) * (1.0f / 7.0f);
            const float bh = fmaxf(roi[4] * SSCALE - y1, 0.1f) * (1.0f / 7.0f);

            float y = y1 + ((float)ph + sy) * bh;
            y = fminf(fmaxf(y, 0.0f), 127.0f);
            float y0f = floorf(y);
            int   y0  = (int)y0f;
            float ly  = y - y0f;
            if (y0 > 126) { y0 = 126; ly = 1.0f; }   // y==127 -> full weight on row 127

            float x = x1 + ((float)pw + sx) * bw;
            x = fminf(fmaxf(x, 0.0f), 127.0f);
            float x0f = floorf(x);
            int   x0  = (int)x0f;
            float lx  = x - x0f;
            if (x0 > 126) { x0 = 126; lx = 1.0f; }

            const float* p = plane + y0 * FW + x0;
            const float v00 = p[0];
            const float v01 = p[1];
            const float v10 = p[FW];
            const float v11 = p[FW + 1];

            const float top = v00 + (v01 - v00) * lx;
            const float bot = v10 + (v11 - v10) * lx;
            float val = top + (bot - top) * ly;

            val += __shfl_xor(val, 1);
            val += __shfl_xor(val, 2);
            if (sub == 0) out[(size_t)ri * CPLANE + c_in] = val * 0.25f;
        }
    };
    gather(kb,        r0);
    gather(kb + 256,  r1);
    gather(kb + 512,  r2);
    gather(kb + 768,  r3);
    gather(kb + 1024, r4);
    gather(kb + 1280, r5);
    gather(kb + 1536, r6);
    gather(kb + 1792, r7);
}

extern "C" void kernel_launch(void* const* d_in, const int* in_sizes, int n_in,
                              void* d_out, int out_size, void* d_ws, size_t ws_size,
                              hipStream_t stream) {
    const float* feat = (const float*)d_in[0];
    const float* rois = (const float*)d_in[1];
    float* out = (float*)d_out;

    const int R = in_sizes[1] / 5;   // 2048 (kernel assumes R <= 2048)

    psroi_fused<<<NPLANES, 1024, 0, stream>>>(feat, rois, out, R);
}